// Round 1
// baseline (148.719 us; speedup 1.0000x reference)
//
#include <hip/hip_runtime.h>
#include <math.h>

#define NBATCH 8192
#define NNEI 256
#define NROLE 3
#define NHID 32
#define NDIM 6
#define NCHUNK 4
// 48B record stride: record p's b128 lands in 16B-bank-group (3p mod 8) — a
// perfect permutation over all 8 groups -> near-conflict-free for b128 ops.
#define SSTRIDE 12

typedef float v2f __attribute__((ext_vector_type(2)));
typedef unsigned long long ull;

// MLP score via packed-f32 pairs (v_pk_fma_f32): Linear(6,32)->ReLU->Linear(32,1).
// Weight pointers MUST be wave-uniform (role is a compile-time unrolled loop
// index here) so weight reads stay s_load scalar traffic — R5: losing this = 4x.
__device__ __forceinline__ float mlp_score(const float x0, const float x1,
                                           const float x2, const float x3,
                                           const float x4, const float x5,
                                           const float* __restrict__ w1,
                                           const float* __restrict__ bb,
                                           const float* __restrict__ w2,
                                           const float b2v) {
  const float x[NDIM] = {x0, x1, x2, x3, x4, x5};
  v2f ac0 = {0.f, 0.f}, ac1 = {0.f, 0.f}, ac2 = {0.f, 0.f}, ac3 = {0.f, 0.f};
#pragma unroll
  for (int h = 0; h < NHID; h += 8) {
    v2f a0 = *(const v2f*)(bb + h + 0);
    v2f a1 = *(const v2f*)(bb + h + 2);
    v2f a2 = *(const v2f*)(bb + h + 4);
    v2f a3 = *(const v2f*)(bb + h + 6);
#pragma unroll
    for (int d = 0; d < NDIM; ++d) {
      const float xv = x[d];
      const v2f xv2 = {xv, xv};
      const float* wc = w1 + d * NHID + h;  // uniform addr -> s_load
      a0 += xv2 * (*(const v2f*)(wc + 0));  // -ffp-contract -> v_pk_fma_f32
      a1 += xv2 * (*(const v2f*)(wc + 2));
      a2 += xv2 * (*(const v2f*)(wc + 4));
      a3 += xv2 * (*(const v2f*)(wc + 6));
    }
    a0.x = fmaxf(a0.x, 0.f); a0.y = fmaxf(a0.y, 0.f);
    a1.x = fmaxf(a1.x, 0.f); a1.y = fmaxf(a1.y, 0.f);
    a2.x = fmaxf(a2.x, 0.f); a2.y = fmaxf(a2.y, 0.f);
    a3.x = fmaxf(a3.x, 0.f); a3.y = fmaxf(a3.y, 0.f);
    ac0 += a0 * (*(const v2f*)(w2 + h + 0));
    ac1 += a1 * (*(const v2f*)(w2 + h + 2));
    ac2 += a2 * (*(const v2f*)(w2 + h + 4));
    ac3 += a3 * (*(const v2f*)(w2 + h + 6));
  }
  const v2f st = (ac0 + ac1) + (ac2 + ac3);
  return b2v + st.x + st.y;
}

// Wave-per-batch design: one 64-lane wave owns one batch end-to-end.
//  - All 4 chunks (256 neighbors) of loads issued up-front (~9.25 KB in
//    flight per wave) -> HBM saturation with ~13 independent waves/CU.
//  - Ballot-sort by role into a wave-PRIVATE LDS region: no s_barrier at all,
//    only an lgkmcnt(0) between the wave's own ds_writes and ds_reads.
//  - 3 sequential role passes with compile-time role index -> wave-uniform
//    weights (scalar loads), dense lanes over each role's sorted list.
// Softmax max-subtraction cancels exactly in mf = sum(e*tw*v)/sum(e*tw)
// (exp(-m) divides out; only the 1e-8 epsilons break it, ~1e-10 relative;
// scores are O(1..12) so exp cannot overflow) — so we skip the max chain.
__global__ __launch_bounds__(64, 4) void hmf_wave(
    const float* __restrict__ states,
    const int* __restrict__ roles,
    const int* __restrict__ maskp,   // bool arrives as int32
    const float* __restrict__ trust,
    const float* __restrict__ W1,    // [R][D][H]
    const float* __restrict__ b1,    // [R][H]
    const float* __restrict__ W2,    // [R][H]
    const float* __restrict__ b2g,   // [R]
    float* __restrict__ out) {
  const int b = blockIdx.x;
  const int lane = threadIdx.x;  // block == one wave

  __shared__ float ssort[NNEI * SSTRIDE];  // 12 KB, wave-private

  const size_t rowb = (size_t)b * NNEI;

  // ---- load all 4 chunks up-front (max bytes-in-flight, coalesced) ----
  int rl[NCHUNK];
  int mk[NCHUNK];
  float tw[NCHUNK];
  float2 sA[NCHUNK], sB[NCHUNK], sC[NCHUNK];
#pragma unroll
  for (int c = 0; c < NCHUNK; ++c) {
    const size_t idx = rowb + (size_t)(c * 64 + lane);
    rl[c] = roles[idx];
    mk[c] = maskp[idx];
    tw[c] = trust[idx];
    const float* sp = states + idx * (size_t)NDIM;
    sA[c] = *(const float2*)(sp);
    sB[c] = *(const float2*)(sp + 2);
    sC[c] = *(const float2*)(sp + 4);
  }

  // ---- per-chunk per-role counts (ballots are wave-uniform -> SALU) ----
  int c0[NCHUNK], c1[NCHUNK], c2[NCHUNK];
#pragma unroll
  for (int c = 0; c < NCHUNK; ++c) {
    const bool a = (mk[c] != 0);
    c0[c] = __popcll(__ballot(a && rl[c] == 0));
    c1[c] = __popcll(__ballot(a && rl[c] == 1));
    c2[c] = __popcll(__ballot(a && rl[c] == 2));
  }
  const int t0 = c0[0] + c0[1] + c0[2] + c0[3];
  const int t1 = c1[0] + c1[1] + c1[2] + c1[3];
  const int t2 = c2[0] + c2[1] + c2[2] + c2[3];

  // ---- sorted dense scatter: [role0 | role1 | role2], chunk-ordered ----
  int p0 = 0, p1 = 0, p2 = 0;  // per-role prefix over earlier chunks
#pragma unroll
  for (int c = 0; c < NCHUNK; ++c) {
    const bool a = (mk[c] != 0);
    const ull balA = __ballot(a && rl[c] == 0);
    const ull balB = __ballot(a && rl[c] == 1);
    const ull balC = __ballot(a && rl[c] == 2);
    if (a) {
      const int r = rl[c];
      const ull mybal = (r == 0) ? balA : (r == 1) ? balB : balC;
      const int rank = __popcll(mybal & ((1ull << lane) - 1ull));
      const int base = (r == 0) ? 0 : (r == 1) ? t0 : (t0 + t1);
      const int pre = (r == 0) ? p0 : (r == 1) ? p1 : p2;
      float* dst = ssort + (size_t)(base + pre + rank) * SSTRIDE;
      *(float4*)(dst) = make_float4(sA[c].x, sA[c].y, sB[c].x, sB[c].y);
      *(float4*)(dst + 4) = make_float4(sC[c].x, sC[c].y, tw[c], 0.f);
    }
    p0 += c0[c];
    p1 += c1[c];
    p2 += c2[c];
  }

  // Wave-coherent LDS: no s_barrier needed, just drain our own ds_writes.
  __asm__ __volatile__("s_waitcnt lgkmcnt(0)" ::: "memory");

  const size_t rowo = (size_t)b * (NROLE * NDIM);

  // ---- 3 role passes, each dense over that role's sorted list ----
#pragma unroll
  for (int r = 0; r < NROLE; ++r) {
    const int cr = __builtin_amdgcn_readfirstlane((r == 0) ? t0 : (r == 1) ? t1 : t2);
    const int br = __builtin_amdgcn_readfirstlane((r == 0) ? 0 : (r == 1) ? t0 : (t0 + t1));
    const float* w1 = W1 + r * (NDIM * NHID);
    const float* bb = b1 + r * NHID;
    const float* w2 = W2 + r * NHID;
    const float b2v = b2g[r];

    float q0 = 0.f, q1 = 0.f, q2 = 0.f, q3 = 0.f,
          q4 = 0.f, q5 = 0.f, q6 = 0.f, q7 = 0.f;  // {Se, Set, Sd0..Sd5}
    // cr <= 64 with P ~ 1 (binomial(128,1/3)); loop runs 0-1 iters, handles
    // the pathological cr>64 case for free. Only written slots are read ->
    // no NaN-gating needed.
    for (int j = lane; j < cr; j += 64) {
      const float* s = ssort + (size_t)(br + j) * SSTRIDE;
      const float4 v4 = *(const float4*)(s);
      const float4 vb = *(const float4*)(s + 4);
      const float sc = mlp_score(v4.x, v4.y, v4.z, v4.w, vb.x, vb.y, w1, bb, w2, b2v);
      const float e = __expf(sc);
      const float et = e * vb.z;
      q0 += e;
      q1 += et;
      q2 = fmaf(et, v4.x, q2);
      q3 = fmaf(et, v4.y, q3);
      q4 = fmaf(et, v4.z, q4);
      q5 = fmaf(et, v4.w, q5);
      q6 = fmaf(et, vb.x, q6);
      q7 = fmaf(et, vb.y, q7);
    }

    // ---- reduction: 3 xor steps x8 (independent), select, 3 xor steps x1 ----
#pragma unroll
    for (int off = 1; off <= 4; off <<= 1) {
      q0 += __shfl_xor(q0, off); q1 += __shfl_xor(q1, off);
      q2 += __shfl_xor(q2, off); q3 += __shfl_xor(q3, off);
      q4 += __shfl_xor(q4, off); q5 += __shfl_xor(q5, off);
      q6 += __shfl_xor(q6, off); q7 += __shfl_xor(q7, off);
    }
    const int g = lane & 7;
    float myq = q0;
    myq = (g == 1) ? q1 : myq;
    myq = (g == 2) ? q2 : myq;
    myq = (g == 3) ? q3 : myq;
    myq = (g == 4) ? q4 : myq;
    myq = (g == 5) ? q5 : myq;
    myq = (g == 6) ? q6 : myq;
    myq = (g == 7) ? q7 : myq;
    myq += __shfl_xor(myq, 8);
    myq += __shfl_xor(myq, 16);
    myq += __shfl_xor(myq, 32);
    // lane i now holds the 64-lane total of quantity (i & 7)
    const float Se = __shfl(myq, 0);
    const float Set = __shfl(myq, 1);
    const float denom = Se + 1e-8f;
    const float ws = fmaxf(Set / denom, 1e-8f);
    if (lane >= 2 && lane < 8) {
      out[rowo + r * NDIM + (lane - 2)] = (myq / denom) / ws;
    }
  }
}

extern "C" void kernel_launch(void* const* d_in, const int* in_sizes, int n_in,
                              void* d_out, int out_size, void* d_ws, size_t ws_size,
                              hipStream_t stream) {
  const float* states = (const float*)d_in[0];
  const int* roles = (const int*)d_in[1];
  const int* maskp = (const int*)d_in[2];
  const float* trust = (const float*)d_in[3];
  const float* W1 = (const float*)d_in[4];
  const float* b1 = (const float*)d_in[5];
  const float* W2 = (const float*)d_in[6];
  const float* b2 = (const float*)d_in[7];
  float* out = (float*)d_out;

  hmf_wave<<<NBATCH, 64, 0, stream>>>(states, roles, maskp, trust, W1, b1, W2, b2, out);
}

// Round 2
// 118.931 us; speedup vs baseline: 1.2505x; 1.2505x over previous
//
#include <hip/hip_runtime.h>
#include <math.h>

#define NBATCH 8192
#define NNEI 256
#define NROLE 3
#define NHID 32
#define NDIM 6
// 48B record stride: record p's b128 lands in 16B-bank-group (3p mod 8) — a
// perfect permutation over all 8 groups -> near-conflict-free for b128/b64/b32.
// (R9 measured stride 16 floats = 64B -> only 2 groups -> 1.7M conflict cycles.)
#define SSTRIDE 12

typedef float v2f __attribute__((ext_vector_type(2)));
typedef unsigned long long ull;

// Compiler-fenced lgkm-only barrier (CK "block_sync_lds" idiom): unlike
// __syncthreads(), does NOT drain vmcnt — any global loads stay in flight.
// imm 0xC07F: vmcnt=63, expcnt=7, lgkmcnt=0.
__device__ __forceinline__ void barrier_lds_only() {
  __asm__ __volatile__("" ::: "memory");
  __builtin_amdgcn_s_waitcnt(0xC07F);
  __builtin_amdgcn_s_barrier();
  __asm__ __volatile__("" ::: "memory");
}

// MLP score via packed-f32 pairs (v_pk_fma_f32): Linear(6,32)->ReLU->Linear(32,1).
// Weight pointers MUST be wave-uniform (readfirstlane'd role) so weight reads
// stay s_load scalar traffic — R5 showed losing this costs 4x.
__device__ __forceinline__ float mlp_score(const float x0, const float x1,
                                           const float x2, const float x3,
                                           const float x4, const float x5,
                                           const float* __restrict__ w1,
                                           const float* __restrict__ bb,
                                           const float* __restrict__ w2,
                                           const float b2v) {
  const float x[NDIM] = {x0, x1, x2, x3, x4, x5};
  v2f ac0 = {0.f, 0.f}, ac1 = {0.f, 0.f}, ac2 = {0.f, 0.f}, ac3 = {0.f, 0.f};
#pragma unroll
  for (int h = 0; h < NHID; h += 8) {
    v2f a0 = *(const v2f*)(bb + h + 0);
    v2f a1 = *(const v2f*)(bb + h + 2);
    v2f a2 = *(const v2f*)(bb + h + 4);
    v2f a3 = *(const v2f*)(bb + h + 6);
#pragma unroll
    for (int d = 0; d < NDIM; ++d) {
      const float xv = x[d];
      const v2f xv2 = {xv, xv};
      const float* wc = w1 + d * NHID + h;  // uniform addr -> s_load
      a0 += xv2 * (*(const v2f*)(wc + 0));  // -ffp-contract -> v_pk_fma_f32
      a1 += xv2 * (*(const v2f*)(wc + 2));
      a2 += xv2 * (*(const v2f*)(wc + 4));
      a3 += xv2 * (*(const v2f*)(wc + 6));
    }
    a0.x = fmaxf(a0.x, 0.f); a0.y = fmaxf(a0.y, 0.f);
    a1.x = fmaxf(a1.x, 0.f); a1.y = fmaxf(a1.y, 0.f);
    a2.x = fmaxf(a2.x, 0.f); a2.y = fmaxf(a2.y, 0.f);
    a3.x = fmaxf(a3.x, 0.f); a3.y = fmaxf(a3.y, 0.f);
    ac0 += a0 * (*(const v2f*)(w2 + h + 0));
    ac1 += a1 * (*(const v2f*)(w2 + h + 2));
    ac2 += a2 * (*(const v2f*)(w2 + h + 4));
    ac3 += a3 * (*(const v2f*)(w2 + h + 6));
  }
  const v2f st = (ac0 + ac1) + (ac2 + ac3);
  return b2v + st.x + st.y;
}

// 192-thread blocks (3 waves): wave r owns role r in phase 3 -> NO idle wave
// (the 256-thread version idled wave 3: 24 working waves/CU of 32 resident;
// this gets 10 blocks/CU = 30 resident waves, all working).
// Wave 0 additionally handles chunk 3 in phase 1 (loads issued together, so
// latency overlaps; waves 1-2 just reach the barrier early).
// Softmax max-subtraction cancels exactly in mf = sum(e*tw*v)/sum(e*tw)
// (exp(-m) divides out; only the 1e-8 epsilons break it, ~1e-10 relative;
// scores are O(1..12) so exp cannot overflow) — so we skip the max chain.
__global__ __launch_bounds__(192) void hmf_main(
    const float* __restrict__ states,
    const int* __restrict__ roles,
    const int* __restrict__ maskp,   // bool arrives as int32
    const float* __restrict__ trust,
    const float* __restrict__ W1,    // [R][D][H]
    const float* __restrict__ b1,    // [R][H]
    const float* __restrict__ W2,    // [R][H]
    const float* __restrict__ b2g,   // [R]
    float* __restrict__ out) {
  const int b = blockIdx.x;
  const int tid = threadIdx.x;
  const int wave = tid >> 6;   // 0..2
  const int lane = tid & 63;

  __shared__ float ssort[NNEI * SSTRIDE];  // 12 KB; chunk c owns slots [64c,64c+64)
  __shared__ int scnt[12];                 // [c*3+r]

  const size_t rowb = (size_t)b * NNEI;

  // ---- phase 1: coalesced loads, per-role ballots, per-chunk sorted scatter ----
  // chunk A = wave; chunk B = 3 (wave 0 only). Issue ALL loads before ballots.
  const size_t idxA = rowb + (size_t)(wave * 64 + lane);
  const int roleA = roles[idxA];
  const int maskA = maskp[idxA];
  const float twA = trust[idxA];
  const float* spA = states + idxA * (size_t)NDIM;
  const float2 aA = *(const float2*)(spA);
  const float2 aB = *(const float2*)(spA + 2);
  const float2 aC = *(const float2*)(spA + 4);

  const bool have2 = (wave == 0);
  int roleB = 0, maskB = 0;
  float twB = 0.f;
  float2 bA = {0.f, 0.f}, bB = {0.f, 0.f}, bC = {0.f, 0.f};
  if (have2) {
    const size_t idxB = rowb + (size_t)(192 + lane);
    roleB = roles[idxB];
    maskB = maskp[idxB];
    twB = trust[idxB];
    const float* spB = states + idxB * (size_t)NDIM;
    bA = *(const float2*)(spB);
    bB = *(const float2*)(spB + 2);
    bC = *(const float2*)(spB + 4);
  }

  {  // chunk A (c = wave)
    const bool active = (maskA != 0);
    const ull bal0 = __ballot(active && (roleA == 0));
    const ull bal1 = __ballot(active && (roleA == 1));
    const ull bal2 = __ballot(active && (roleA == 2));
    const int c0 = __popcll(bal0);
    const int c1 = __popcll(bal1);
    if (lane < 3) {
      const int c2 = __popcll(bal2);
      scnt[wave * 3 + lane] = (lane == 0) ? c0 : (lane == 1) ? c1 : c2;
    }
    if (active) {
      const ull mybal = (roleA == 0) ? bal0 : (roleA == 1) ? bal1 : bal2;
      const int rank = __popcll(mybal & ((1ull << lane) - 1ull));
      const int pre = ((roleA >= 1) ? c0 : 0) + ((roleA >= 2) ? c1 : 0);
      const int pos = wave * 64 + pre + rank;  // chunk-private region
      float* dst = ssort + pos * SSTRIDE;
      *(float4*)dst = make_float4(aA.x, aA.y, aB.x, aB.y);
      *(float4*)(dst + 4) = make_float4(aC.x, aC.y, twA, 0.f);
    }
  }
  if (have2) {  // chunk B (c = 3), wave 0 only — ballots are whole-wave here
    const bool active = (maskB != 0);
    const ull bal0 = __ballot(active && (roleB == 0));
    const ull bal1 = __ballot(active && (roleB == 1));
    const ull bal2 = __ballot(active && (roleB == 2));
    const int c0 = __popcll(bal0);
    const int c1 = __popcll(bal1);
    if (lane < 3) {
      const int c2 = __popcll(bal2);
      scnt[9 + lane] = (lane == 0) ? c0 : (lane == 1) ? c1 : c2;
    }
    if (active) {
      const ull mybal = (roleB == 0) ? bal0 : (roleB == 1) ? bal1 : bal2;
      const int rank = __popcll(mybal & ((1ull << lane) - 1ull));
      const int pre = ((roleB >= 1) ? c0 : 0) + ((roleB >= 2) ? c1 : 0);
      const int pos = 192 + pre + rank;
      float* dst = ssort + pos * SSTRIDE;
      *(float4*)dst = make_float4(bA.x, bA.y, bB.x, bB.y);
      *(float4*)(dst + 4) = make_float4(bC.x, bC.y, twB, 0.f);
    }
  }
  barrier_lds_only();  // the ONLY barrier

  // ---- phase 3: wave r handles role r across the 4 chunk-segments ----
  {
    const int r = __builtin_amdgcn_readfirstlane(wave);
    int cwv[4], prw[4];
#pragma unroll
    for (int w = 0; w < 4; ++w) {
      const int a0 = scnt[w * 3 + 0];
      const int a1 = scnt[w * 3 + 1];
      const int a2 = scnt[w * 3 + 2];
      const int cv = (r == 0) ? a0 : (r == 1) ? a1 : a2;
      const int pv = ((r >= 1) ? a0 : 0) + ((r >= 2) ? a1 : 0);
      cwv[w] = __builtin_amdgcn_readfirstlane(cv);
      prw[w] = __builtin_amdgcn_readfirstlane(pv);
    }
    const int acc0 = cwv[0];
    const int acc1 = acc0 + cwv[1];
    const int acc2 = acc1 + cwv[2];
    const int cnt = acc2 + cwv[3];

    const float* w1 = W1 + r * (NDIM * NHID);
    const float* bb = b1 + r * NHID;
    const float* w2 = W2 + r * NHID;
    const float b2v = b2g[r];

    float q0, q1, q2, q3, q4, q5, q6, q7;  // {Se, Set, Sd0..Sd5}

    if (cnt <= 64) {
      // ---- FAST PATH (P ≈ 1 - 1e-4): single chunk, static control flow ----
      const bool act = lane < cnt;
      const bool s1 = lane >= acc0;
      const bool s2 = lane >= acc1;
      const bool s3 = lane >= acc2;
      int sub = s1 ? acc0 : 0; sub = s2 ? acc1 : sub; sub = s3 ? acc2 : sub;
      int wb = s1 ? 64 : 0;    wb = s2 ? 128 : wb;    wb = s3 ? 192 : wb;
      int pr = s1 ? prw[1] : prw[0]; pr = s2 ? prw[2] : pr; pr = s3 ? prw[3] : pr;
      int pos = wb + pr + (lane - sub);
      pos = (pos > NNEI - 1) ? (NNEI - 1) : pos;  // inactive lanes may overrun
      const float* s = ssort + pos * SSTRIDE;
      float4 v4 = *(const float4*)s;
      float4 vb = *(const float4*)(s + 4);
      float tw = vb.z;
      if (!act) {  // select-gate: garbage slots may hold NaN
        v4 = make_float4(0.f, 0.f, 0.f, 0.f);
        vb = make_float4(0.f, 0.f, 0.f, 0.f);
        tw = 0.f;
      }
      const float sc = mlp_score(v4.x, v4.y, v4.z, v4.w, vb.x, vb.y, w1, bb, w2, b2v);
      const float e = act ? __expf(sc) : 0.f;
      const float et = e * tw;
      q0 = e; q1 = et;
      q2 = et * v4.x; q3 = et * v4.y; q4 = et * v4.z;
      q5 = et * v4.w; q6 = et * vb.x; q7 = et * vb.y;
    } else {
      // ---- SLOW PATH (cold, ~3 lists in 24576): dynamic chunk loop ----
      q0 = q1 = q2 = q3 = q4 = q5 = q6 = q7 = 0.f;
      const int nch = (cnt + 63) >> 6;
      for (int c = 0; c < nch; ++c) {
        const int jj = c * 64 + lane;
        const bool act = jj < cnt;
        const bool s1 = jj >= acc0;
        const bool s2 = jj >= acc1;
        const bool s3 = jj >= acc2;
        int sub = s1 ? acc0 : 0; sub = s2 ? acc1 : sub; sub = s3 ? acc2 : sub;
        int wb = s1 ? 64 : 0;    wb = s2 ? 128 : wb;    wb = s3 ? 192 : wb;
        int pr = s1 ? prw[1] : prw[0]; pr = s2 ? prw[2] : pr; pr = s3 ? prw[3] : pr;
        int pos = wb + pr + (jj - sub);
        pos = (pos > NNEI - 1) ? (NNEI - 1) : pos;
        pos = (pos < 0) ? 0 : pos;
        const float* s = ssort + pos * SSTRIDE;
        float4 v4 = *(const float4*)s;
        float4 vb = *(const float4*)(s + 4);
        float tw = vb.z;
        if (!act) {
          v4 = make_float4(0.f, 0.f, 0.f, 0.f);
          vb = make_float4(0.f, 0.f, 0.f, 0.f);
          tw = 0.f;
        }
        const float sc = mlp_score(v4.x, v4.y, v4.z, v4.w, vb.x, vb.y, w1, bb, w2, b2v);
        const float e = act ? __expf(sc) : 0.f;
        const float et = e * tw;
        q0 += e; q1 += et;
        q2 = fmaf(et, v4.x, q2); q3 = fmaf(et, v4.y, q3);
        q4 = fmaf(et, v4.z, q4); q5 = fmaf(et, v4.w, q5);
        q6 = fmaf(et, vb.x, q6); q7 = fmaf(et, vb.y, q7);
      }
    }

    // ---- reduction: 3 xor steps x8 (independent), select, 3 xor steps x1 ----
#pragma unroll
    for (int off = 1; off <= 4; off <<= 1) {
      q0 += __shfl_xor(q0, off); q1 += __shfl_xor(q1, off);
      q2 += __shfl_xor(q2, off); q3 += __shfl_xor(q3, off);
      q4 += __shfl_xor(q4, off); q5 += __shfl_xor(q5, off);
      q6 += __shfl_xor(q6, off); q7 += __shfl_xor(q7, off);
    }
    const int g = lane & 7;
    float myq = q0;
    myq = (g == 1) ? q1 : myq;
    myq = (g == 2) ? q2 : myq;
    myq = (g == 3) ? q3 : myq;
    myq = (g == 4) ? q4 : myq;
    myq = (g == 5) ? q5 : myq;
    myq = (g == 6) ? q6 : myq;
    myq = (g == 7) ? q7 : myq;
    myq += __shfl_xor(myq, 8);
    myq += __shfl_xor(myq, 16);
    myq += __shfl_xor(myq, 32);
    // lane i now holds the 64-lane total of quantity (i & 7)
    const float Se = __shfl(myq, 0);
    const float Set = __shfl(myq, 1);
    const float denom = Se + 1e-8f;
    const float ws = fmaxf(Set / denom, 1e-8f);
    if (lane >= 2 && lane < 8) {
      out[(size_t)b * (NROLE * NDIM) + r * NDIM + (lane - 2)] = (myq / denom) / ws;
    }
  }
}

extern "C" void kernel_launch(void* const* d_in, const int* in_sizes, int n_in,
                              void* d_out, int out_size, void* d_ws, size_t ws_size,
                              hipStream_t stream) {
  const float* states = (const float*)d_in[0];
  const int* roles = (const int*)d_in[1];
  const int* maskp = (const int*)d_in[2];
  const float* trust = (const float*)d_in[3];
  const float* W1 = (const float*)d_in[4];
  const float* b1 = (const float*)d_in[5];
  const float* W2 = (const float*)d_in[6];
  const float* b2 = (const float*)d_in[7];
  float* out = (float*)d_out;

  hmf_main<<<NBATCH, 192, 0, stream>>>(states, roles, maskp, trust, W1, b1, W2, b2, out);
}